// Round 15
// baseline (134.388 us; speedup 1.0000x reference)
//
#include <hip/hip_runtime.h>

static constexpr int NN   = 50000;   // nodes
static constexpr int NE   = 800000;  // edges
static constexpr int FIN  = 128;
static constexpr int FOUT = 64;
static constexpr int GEMM_NBLK = (NN + 63) / 64;     // 782 row-blocks
static constexpr int CAP  = 64;                      // bucket capacity/node
static constexpr int NRANGE = 8;                     // ranges for k_agg mapping
static constexpr int RSZ  = NN / NRANGE;             // 6250 nodes/range
static constexpr int AGG_NBLK = 2048;                // 256 blocks/range

static constexpr int NRG    = 196;                   // fine ranges: dst>>8
static constexpr int CAPSEG = 5120;                  // per-range segment cap
static constexpr int PA_NBLK = 98;                   // passA: 1024thr x 8 edges
static constexpr int BB_NBLK = NRG * 2;              // 392 half-range blocks

static constexpr int WT_LD = 136;                    // W^T padded row (ushorts)

typedef short bf16x8 __attribute__((ext_vector_type(8)));
typedef float f32x4  __attribute__((ext_vector_type(4)));

// float -> bf16 round-to-nearest-even
static __device__ __forceinline__ unsigned short f2bf(float f) {
    unsigned u = __float_as_uint(f);
    u += 0x7FFFu + ((u >> 16) & 1u);
    return (unsigned short)(u >> 16);
}
static __device__ __forceinline__ float bf2f(unsigned short b) {
    return __uint_as_float(((unsigned)b) << 16);
}

// ---------------- Pass A: coarse LDS-binned edge partition (round-11) -----
__global__ __launch_bounds__(1024) void k_binA(
    const int* __restrict__ src, const int* __restrict__ dst,
    int* __restrict__ rangeCursor, unsigned int* __restrict__ epack)
{
    __shared__ int hist[NRG];
    __shared__ int base[NRG];
    const int t = threadIdx.x;
    for (int i = t; i < NRG; i += 1024) hist[i] = 0;
    __syncthreads();

    const int g = blockIdx.x * 1024 + t;       // 8-edge group id
    const bool act = g < NE / 8;               // NE/8 = 100000 exactly
    int dd[8], ss[8], rk[8], bn[8];
    if (act) {
        const int4 d0 = ((const int4*)dst)[g * 2];
        const int4 d1 = ((const int4*)dst)[g * 2 + 1];
        const int4 s0 = ((const int4*)src)[g * 2];
        const int4 s1 = ((const int4*)src)[g * 2 + 1];
        dd[0]=d0.x; dd[1]=d0.y; dd[2]=d0.z; dd[3]=d0.w;
        dd[4]=d1.x; dd[5]=d1.y; dd[6]=d1.z; dd[7]=d1.w;
        ss[0]=s0.x; ss[1]=s0.y; ss[2]=s0.z; ss[3]=s0.w;
        ss[4]=s1.x; ss[5]=s1.y; ss[6]=s1.z; ss[7]=s1.w;
        #pragma unroll
        for (int u = 0; u < 8; ++u) {
            bn[u] = dd[u] >> 8;
            rk[u] = atomicAdd(&hist[bn[u]], 1);    // LDS: local rank
        }
    }
    __syncthreads();
    for (int i = t; i < NRG; i += 1024)            // reserve per-range space
        base[i] = hist[i] ? atomicAdd(&rangeCursor[i], hist[i]) : 0;
    __syncthreads();
    if (act) {
        #pragma unroll
        for (int u = 0; u < 8; ++u) {
            const int pos = base[bn[u]] + rk[u];
            if (pos < CAPSEG)                      // +16 sigma, never trips
                epack[bn[u] * CAPSEG + pos] =
                    ((unsigned)dd[u] << 16) | (unsigned)ss[u];
        }
    }
}

// ---------------- Kernel 2: MFMA GEMM (round-13 role, standalone) ---------
__global__ __launch_bounds__(256) void k_gemm(
    const float* __restrict__ x, const float* __restrict__ W,
    const float* __restrict__ att_src, const float* __restrict__ att_dst,
    unsigned short* __restrict__ hb, float* __restrict__ ssrc,
    float* __restrict__ sdst)
{
    __shared__ alignas(16) unsigned short SML[64 * WT_LD + 4 * 1024]; // 25.6KB
    const int t = threadIdx.x;

    const float4* W4 = (const float4*)W;             // W is [k][n] fp32
    for (int i = t; i < 2048; i += 256) {            // i = float4 index
        const float4 w4 = W4[i];
        const int k = i >> 4, n0 = (i & 15) << 2;
        SML[(n0+0) * WT_LD + k] = f2bf(w4.x);
        SML[(n0+1) * WT_LD + k] = f2bf(w4.y);
        SML[(n0+2) * WT_LD + k] = f2bf(w4.z);
        SML[(n0+3) * WT_LD + k] = f2bf(w4.w);
    }
    __syncthreads();

    const int wave  = t >> 6;
    const int lane  = t & 63;
    const int row16 = lane & 15;      // A row within tile / D col low bits
    const int kblk  = lane >> 4;      // 0..3: k-subblock / D row group
    const int rbase = blockIdx.x * 64 + wave * 16;

    int rowA = rbase + row16; if (rowA >= NN) rowA = NN - 1;   // clamped load
    const float* xrow = x + (size_t)rowA * FIN;

    f32x4 acc0 = {0,0,0,0}, acc1 = {0,0,0,0}, acc2 = {0,0,0,0}, acc3 = {0,0,0,0};

    #pragma unroll
    for (int ks = 0; ks < 4; ++ks) {
        const int k0 = ks * 32 + kblk * 8;           // this lane's 8 k's
        const float4 xa = *(const float4*)(xrow + k0);
        const float4 xb = *(const float4*)(xrow + k0 + 4);
        bf16x8 af;
        af[0] = (short)f2bf(xa.x); af[1] = (short)f2bf(xa.y);
        af[2] = (short)f2bf(xa.z); af[3] = (short)f2bf(xa.w);
        af[4] = (short)f2bf(xb.x); af[5] = (short)f2bf(xb.y);
        af[6] = (short)f2bf(xb.z); af[7] = (short)f2bf(xb.w);

        const bf16x8 b0 = *(const bf16x8*)(&SML[(0*16 + row16) * WT_LD + k0]);
        const bf16x8 b1 = *(const bf16x8*)(&SML[(1*16 + row16) * WT_LD + k0]);
        const bf16x8 b2 = *(const bf16x8*)(&SML[(2*16 + row16) * WT_LD + k0]);
        const bf16x8 b3 = *(const bf16x8*)(&SML[(3*16 + row16) * WT_LD + k0]);
        acc0 = __builtin_amdgcn_mfma_f32_16x16x32_bf16(af, b0, acc0, 0, 0, 0);
        acc1 = __builtin_amdgcn_mfma_f32_16x16x32_bf16(af, b1, acc1, 0, 0, 0);
        acc2 = __builtin_amdgcn_mfma_f32_16x16x32_bf16(af, b2, acc2, 0, 0, 0);
        acc3 = __builtin_amdgcn_mfma_f32_16x16x32_bf16(af, b3, acc3, 0, 0, 0);
    }

    // ---- att scalars from fp32 accums ------------------------------------
    float as0 = att_src[ 0 + row16], as1 = att_src[16 + row16];
    float as2 = att_src[32 + row16], as3 = att_src[48 + row16];
    float ad0 = att_dst[ 0 + row16], ad1 = att_dst[16 + row16];
    float ad2 = att_dst[32 + row16], ad3 = att_dst[48 + row16];
    #pragma unroll
    for (int reg = 0; reg < 4; ++reg) {
        float p = acc0[reg]*as0 + acc1[reg]*as1 + acc2[reg]*as2 + acc3[reg]*as3;
        float q = acc0[reg]*ad0 + acc1[reg]*ad1 + acc2[reg]*ad2 + acc3[reg]*ad3;
        #pragma unroll
        for (int m = 1; m <= 8; m <<= 1) {           // reduce 16 col-lanes
            p += __shfl_xor(p, m, 64);
            q += __shfl_xor(q, m, 64);
        }
        if (row16 == 0) {
            const int r = rbase + kblk * 4 + reg;    // D row
            if (r < NN) { ssrc[r] = p; sdst[r] = q; }
        }
    }

    // ---- h write: transpose via LDS for coalesced 32B global stores ------
    unsigned short* hT = SML + 64 * WT_LD + wave * 1024;   // 16x64 ushorts
    #pragma unroll
    for (int reg = 0; reg < 4; ++reg) {
        const int rr = (kblk * 4 + reg) * 64;
        hT[rr +  0 + row16] = f2bf(acc0[reg]);
        hT[rr + 16 + row16] = f2bf(acc1[reg]);
        hT[rr + 32 + row16] = f2bf(acc2[reg]);
        hT[rr + 48 + row16] = f2bf(acc3[reg]);
    }
    __syncthreads();
    {
        const int rr = lane >> 2;                    // 0..15 tile row
        const int cc = (lane & 3) << 4;              // ushort col base
        const int grow = rbase + rr;
        if (grow < NN) {
            const uint4 v0 = *(const uint4*)(hT + rr * 64 + cc);
            const uint4 v1 = *(const uint4*)(hT + rr * 64 + cc + 8);
            *(uint4*)(hb + (size_t)grow * FOUT + cc)     = v0;
            *(uint4*)(hb + (size_t)grow * FOUT + cc + 8) = v1;
        }
    }
}

// ---------------- Kernel 3: pass-B fine binning + ALPHA precompute --------
// Runs AFTER gemm (needs ssrc/sdst). Block r2 owns 128 nodes (range r2>>1,
// half r2&1). Per kept edge: gather ssrc[s] + sdst[d], sigmoid(leaky) ONCE,
// store (alpha_u16<<16 | src16) in 4B bucket slot via LDS cursor atomics.
// This removes the per-slot sigmoid + ssrc gather from k_agg entirely
// (there they were recomputed per slot on k_agg's critical VALU path).
__global__ __launch_bounds__(256) void k_binB(
    const int* __restrict__ rangeCursor, const unsigned int* __restrict__ epack,
    const float* __restrict__ ssrc, const float* __restrict__ sdst,
    int* __restrict__ counts, unsigned int* __restrict__ bkt4)
{
    __shared__ int cur[128];
    const int t = threadIdx.x;
    const int r    = blockIdx.x >> 1;          // 0..195
    const int half = blockIdx.x & 1;
    if (t < 128) cur[t] = 0;
    __syncthreads();
    int nE = rangeCursor[r];
    if (nE > CAPSEG) nE = CAPSEG;

    for (int i0 = t * 4; i0 < nE; i0 += 1024) {
        // uint4-aligned batch (i0 % 4 == 0); tail beyond nE masked below
        const uint4 pq = *(const uint4*)(epack + r * CAPSEG + i0);
        const unsigned pp[4] = {pq.x, pq.y, pq.z, pq.w};
        bool in[4]; int dd[4], ss[4];
        float zs[4], zd[4];
        #pragma unroll
        for (int u = 0; u < 4; ++u) {
            dd[u] = (int)(pp[u] >> 16);
            ss[u] = (int)(pp[u] & 0xFFFFu);
            in[u] = (i0 + u < nE) && (((dd[u] & 255) >> 7) == half);
            zs[u] = in[u] ? ssrc[ss[u]] : 0.f;     // exec-masked gathers,
            zd[u] = in[u] ? sdst[dd[u]] : 0.f;     // all 4 pairs in flight
        }
        #pragma unroll
        for (int u = 0; u < 4; ++u) {
            if (!in[u]) continue;
            float z = zs[u] + zd[u];
            z = fmaxf(z, 0.2f * z);                // leaky_relu(0.2)
            const float a = 1.f / (1.f + __expf(-z));
            const unsigned au = (unsigned)(a * 65535.f + 0.5f);
            const int pos = atomicAdd(&cur[dd[u] & 127], 1);   // LDS atomic
            if (pos < CAP)                         // never trips (deg<<64)
                bkt4[(dd[u] << 6) + pos] = (au << 16) | (unsigned)ss[u];
        }
    }
    __syncthreads();
    const int node = (r << 8) + (half << 7) + t;
    if (t < 128 && node < NN) counts[node] = cur[t];
}

// ---------------- Kernel 4: aggregation, alpha-precomputed ----------------
// Slots are 4B (alpha16|src16): lane(eq,c8) owns 2 slots = one uint2 load.
// No ssrc gathers, no sigmoid, no sdst -- just dequant + h-gather + FMA.
// Stale slots: alpha masked to 0 by slot<cnt; src<=65535 keeps hb read
// in-bounds (8.4MB < ws).
__global__ __launch_bounds__(256) void k_agg(
    const unsigned short* __restrict__ hb, const unsigned int* __restrict__ bkt4,
    const int* __restrict__ counts, const float* __restrict__ bias,
    float* __restrict__ out)
{
    const int r    = blockIdx.x & 7;          // dst range (XCD heuristic)
    const int wave = threadIdx.x >> 6;
    const int lane = threadIdx.x & 63;
    const int eq   = lane >> 3;               // slot-pair group 0..7
    const int c8   = lane & 7;                // col group (8 cols)
    const int c16  = c8 << 3;                 // col base
    const int wstride = (AGG_NBLK >> 3) * 4;  // 1024 wave-slots per range
    constexpr float DEQ = 1.f / 65535.f;
    const float4 bLo = *(const float4*)(bias + c16);
    const float4 bHi = *(const float4*)(bias + c16 + 4);

    for (int local = (blockIdx.x >> 3) * 4 + wave; local < RSZ;
         local += 2 * wstride) {
        const int localB = local + wstride;
        const bool hasB  = localB < RSZ;
        const int nA   = r * RSZ + local;
        const int nB   = hasB ? r * RSZ + localB : nA;
        const int offA = nA << 6;             // uint units
        const int offB = nB << 6;
        int cntA = counts[nA]; if (cntA > CAP) cntA = CAP;
        int cntB = hasB ? counts[nB] : 0; if (cntB > CAP) cntB = CAP;

        float accA[8] = {0,0,0,0,0,0,0,0};
        float accB[8] = {0,0,0,0,0,0,0,0};
        float asumA = 0.f, asumB = 0.f;

        const int nchA = (cntA + 15) >> 4;    // 16 slots per chunk
        const int nchB = (cntB + 15) >> 4;
        const int nch  = nchA > nchB ? nchA : nchB;   // <= 4

        for (int c = 0; c < nch; ++c) {
            const int s0 = (c << 4) + (eq << 1);   // this lane's 2 slots
            const uint2 wA = *(const uint2*)(bkt4 + offA + s0);  // 8B aligned
            const uint2 wB = *(const uint2*)(bkt4 + offB + s0);
            const unsigned a0 = wA.x & 0xFFFFu, a1 = wA.y & 0xFFFFu;
            const unsigned b0 = wB.x & 0xFFFFu, b1 = wB.y & 0xFFFFu;
            const float aA0 = (s0     < cntA) ? (float)(wA.x >> 16) * DEQ : 0.f;
            const float aA1 = (s0 + 1 < cntA) ? (float)(wA.y >> 16) * DEQ : 0.f;
            const float aB0 = (s0     < cntB) ? (float)(wB.x >> 16) * DEQ : 0.f;
            const float aB1 = (s0 + 1 < cntB) ? (float)(wB.y >> 16) * DEQ : 0.f;

            const uint4 hA0 = *(const uint4*)(hb + (size_t)a0 * FOUT + c16);
            const uint4 hA1 = *(const uint4*)(hb + (size_t)a1 * FOUT + c16);
            const uint4 hB0 = *(const uint4*)(hb + (size_t)b0 * FOUT + c16);
            const uint4 hB1 = *(const uint4*)(hb + (size_t)b1 * FOUT + c16);

            const unsigned uA0[4] = {hA0.x, hA0.y, hA0.z, hA0.w};
            const unsigned uA1[4] = {hA1.x, hA1.y, hA1.z, hA1.w};
            const unsigned uB0[4] = {hB0.x, hB0.y, hB0.z, hB0.w};
            const unsigned uB1[4] = {hB1.x, hB1.y, hB1.z, hB1.w};
            #pragma unroll
            for (int k = 0; k < 4; ++k) {
                accA[2*k]   += aA0 * bf2f((unsigned short)(uA0[k] & 0xFFFFu))
                             + aA1 * bf2f((unsigned short)(uA1[k] & 0xFFFFu));
                accA[2*k+1] += aA0 * bf2f((unsigned short)(uA0[k] >> 16))
                             + aA1 * bf2f((unsigned short)(uA1[k] >> 16));
                accB[2*k]   += aB0 * bf2f((unsigned short)(uB0[k] & 0xFFFFu))
                             + aB1 * bf2f((unsigned short)(uB1[k] & 0xFFFFu));
                accB[2*k+1] += aB0 * bf2f((unsigned short)(uB0[k] >> 16))
                             + aB1 * bf2f((unsigned short)(uB1[k] >> 16));
            }
            asumA += aA0 + aA1;
            asumB += aB0 + aB1;
        }

        #pragma unroll
        for (int m = 8; m <= 32; m <<= 1) {   // reduce across the 8 eq groups
            #pragma unroll
            for (int k = 0; k < 8; ++k) {
                accA[k] += __shfl_xor(accA[k], m, 64);
                accB[k] += __shfl_xor(accB[k], m, 64);
            }
            asumA += __shfl_xor(asumA, m, 64);
            asumB += __shfl_xor(asumB, m, 64);
        }

        if (eq == 0) {
            const float invA = 1.f / (asumA + 1e-8f);
            float4 lo, hi;
            lo.x = accA[0]*invA + bLo.x; lo.y = accA[1]*invA + bLo.y;
            lo.z = accA[2]*invA + bLo.z; lo.w = accA[3]*invA + bLo.w;
            hi.x = accA[4]*invA + bHi.x; hi.y = accA[5]*invA + bHi.y;
            hi.z = accA[6]*invA + bHi.z; hi.w = accA[7]*invA + bHi.w;
            *(float4*)(out + (size_t)nA * FOUT + c16)     = lo;
            *(float4*)(out + (size_t)nA * FOUT + c16 + 4) = hi;
            if (hasB) {
                const float invB = 1.f / (asumB + 1e-8f);
                lo.x = accB[0]*invB + bLo.x; lo.y = accB[1]*invB + bLo.y;
                lo.z = accB[2]*invB + bLo.z; lo.w = accB[3]*invB + bLo.w;
                hi.x = accB[4]*invB + bHi.x; hi.y = accB[5]*invB + bHi.y;
                hi.z = accB[6]*invB + bHi.z; hi.w = accB[7]*invB + bHi.w;
                *(float4*)(out + (size_t)nB * FOUT + c16)     = lo;
                *(float4*)(out + (size_t)nB * FOUT + c16 + 4) = hi;
            }
        }
    }
}

// ---------------- launch ---------------------------------------------------
extern "C" void kernel_launch(void* const* d_in, const int* in_sizes, int n_in,
                              void* d_out, int out_size, void* d_ws, size_t ws_size,
                              hipStream_t stream)
{
    const float* x       = (const float*)d_in[0];
    const int*   ei      = (const int*)  d_in[1];   // (2, NE) int32
    const float* W       = (const float*)d_in[2];
    const float* att_src = (const float*)d_in[3];
    const float* att_dst = (const float*)d_in[4];
    const float* bias    = (const float*)d_in[5];
    float* out = (float*)d_out;

    // workspace layout (~24 MB)
    unsigned short* hb  = (unsigned short*)d_ws;            // NN*FOUT bf16, 6.4MB
    float* ssrc         = (float*)(hb + (size_t)NN * FOUT);
    float* sdst         = ssrc + NN;
    int*   counts       = (int*)(sdst + NN);                // NN ints
    unsigned int* bkt4  = (unsigned int*)(counts + NN);     // NN*CAP uint, 12.8MB
    unsigned int* epack = (unsigned int*)(bkt4 + (size_t)NN * CAP); // 4.0MB
    int* rangeCursor    = (int*)(epack + (size_t)NRG * CAPSEG);     // 196 ints

    const int* src = ei;
    const int* dst = ei + NE;

    // zero the per-range segment cursors (tiny)
    (void)hipMemsetAsync(rangeCursor, 0, NRG * sizeof(int), stream);

    k_binA<<<PA_NBLK, 1024, 0, stream>>>(src, dst, rangeCursor, epack);
    k_gemm<<<GEMM_NBLK, 256, 0, stream>>>(x, W, att_src, att_dst,
                                          hb, ssrc, sdst);
    k_binB<<<BB_NBLK, 256, 0, stream>>>(rangeCursor, epack, ssrc, sdst,
                                        counts, bkt4);
    k_agg<<<AGG_NBLK, 256, 0, stream>>>(hb, bkt4, counts, bias, out);
}

// Round 16
// 129.383 us; speedup vs baseline: 1.0387x; 1.0387x over previous
//
#include <hip/hip_runtime.h>

static constexpr int NN   = 50000;   // nodes
static constexpr int NE   = 800000;  // edges
static constexpr int FIN  = 128;
static constexpr int FOUT = 64;
static constexpr int GEMM_NBLK = (NN + 63) / 64;     // 782 row-blocks
static constexpr int CAP  = 64;                      // bucket capacity/node
static constexpr int NRANGE = 8;                     // ranges for k_agg mapping
static constexpr int RSZ  = NN / NRANGE;             // 6250 nodes/range
static constexpr int AGG_NBLK = 2048;                // 256 blocks/range

static constexpr int NRG    = 196;                   // fine ranges: dst>>8
static constexpr int CAPSEG = 5120;                  // per-range segment cap
static constexpr int PA_NBLK = 98;                   // passA: 1024thr x 8 edges
static constexpr int FUSE_NBLK = GEMM_NBLK + NRG;    // 978

static constexpr int WT_LD = 136;                    // W^T padded row (ushorts)

typedef short bf16x8 __attribute__((ext_vector_type(8)));
typedef float f32x4  __attribute__((ext_vector_type(4)));

// float -> bf16 round-to-nearest-even
static __device__ __forceinline__ unsigned short f2bf(float f) {
    unsigned u = __float_as_uint(f);
    u += 0x7FFFu + ((u >> 16) & 1u);
    return (unsigned short)(u >> 16);
}
static __device__ __forceinline__ float bf2f(unsigned short b) {
    return __uint_as_float(((unsigned)b) << 16);
}

// ---------------- Pass A: coarse LDS-binned edge partition (round-11) -----
__global__ __launch_bounds__(1024) void k_binA(
    const int* __restrict__ src, const int* __restrict__ dst,
    int* __restrict__ rangeCursor, unsigned int* __restrict__ epack)
{
    __shared__ int hist[NRG];
    __shared__ int base[NRG];
    const int t = threadIdx.x;
    for (int i = t; i < NRG; i += 1024) hist[i] = 0;
    __syncthreads();

    const int g = blockIdx.x * 1024 + t;       // 8-edge group id
    const bool act = g < NE / 8;               // NE/8 = 100000 exactly
    int dd[8], ss[8], rk[8], bn[8];
    if (act) {
        const int4 d0 = ((const int4*)dst)[g * 2];
        const int4 d1 = ((const int4*)dst)[g * 2 + 1];
        const int4 s0 = ((const int4*)src)[g * 2];
        const int4 s1 = ((const int4*)src)[g * 2 + 1];
        dd[0]=d0.x; dd[1]=d0.y; dd[2]=d0.z; dd[3]=d0.w;
        dd[4]=d1.x; dd[5]=d1.y; dd[6]=d1.z; dd[7]=d1.w;
        ss[0]=s0.x; ss[1]=s0.y; ss[2]=s0.z; ss[3]=s0.w;
        ss[4]=s1.x; ss[5]=s1.y; ss[6]=s1.z; ss[7]=s1.w;
        #pragma unroll
        for (int u = 0; u < 8; ++u) {
            bn[u] = dd[u] >> 8;
            rk[u] = atomicAdd(&hist[bn[u]], 1);    // LDS: local rank
        }
    }
    __syncthreads();
    for (int i = t; i < NRG; i += 1024)            // reserve per-range space
        base[i] = hist[i] ? atomicAdd(&rangeCursor[i], hist[i]) : 0;
    __syncthreads();
    if (act) {
        #pragma unroll
        for (int u = 0; u < 8; ++u) {
            const int pos = base[bn[u]] + rk[u];
            if (pos < CAPSEG)                      // +16 sigma, never trips
                epack[bn[u] * CAPSEG + pos] =
                    ((unsigned)dd[u] << 16) | (unsigned)ss[u];
        }
    }
}

// ---------------- Fused: MFMA-GEMM blocks + pass-B binning blocks ---------
// GEMM role (mfma_f32_16x16x32_bf16): per wave 16 rows x 64 cols, K=128 in
// 4 steps. W^T staged in LDS as bf16 with 136-ushort padded rows.
// Fragment maps: A lane=(row=l&15, k=(l>>4)*8+i); B lane=(col=l&15, same k);
// D col=l&15, row=(l>>4)*4+reg (HW-verified C/D layout; absmax-verified
// round 13 at 0.0078125).
__global__ __launch_bounds__(256) void k_gemm_binB(
    const float* __restrict__ x, const float* __restrict__ W,
    const float* __restrict__ att_src, const float* __restrict__ att_dst,
    unsigned short* __restrict__ hb, float* __restrict__ ssrc,
    float* __restrict__ sdst, const int* __restrict__ rangeCursor,
    const unsigned int* __restrict__ epack, int* __restrict__ counts,
    unsigned short* __restrict__ bkt)
{
    __shared__ alignas(16) unsigned short SML[64 * WT_LD + 4 * 1024]; // 25.6KB
    const int t = threadIdx.x;

    if (blockIdx.x >= GEMM_NBLK) {
        // ---- pass B role: LDS-cursor fine binning ----
        const int r = blockIdx.x - GEMM_NBLK;        // 0..195
        int* cur = (int*)SML;                        // 256 cursors
        cur[t] = 0;
        __syncthreads();
        int nE = rangeCursor[r];
        if (nE > CAPSEG) nE = CAPSEG;
        for (int i = t; i < nE; i += 256) {
            const unsigned p = epack[r * CAPSEG + i];
            const int d16 = (int)(p >> 16);
            const int pos = atomicAdd(&cur[d16 & 255], 1);   // LDS atomic
            if (pos < CAP)                            // never trips (deg<<64)
                bkt[(d16 << 6) + pos] = (unsigned short)(p & 0xFFFFu);
        }
        __syncthreads();
        const int node = (r << 8) + t;
        if (node < NN) counts[node] = cur[t];
        return;
    }

    // ---- stage W^T (bf16) into LDS: [n][k], padded stride WT_LD ----------
    const float4* W4 = (const float4*)W;             // W is [k][n] fp32
    for (int i = t; i < 2048; i += 256) {            // i = float4 index
        const float4 w4 = W4[i];
        const int k = i >> 4, n0 = (i & 15) << 2;
        SML[(n0+0) * WT_LD + k] = f2bf(w4.x);
        SML[(n0+1) * WT_LD + k] = f2bf(w4.y);
        SML[(n0+2) * WT_LD + k] = f2bf(w4.z);
        SML[(n0+3) * WT_LD + k] = f2bf(w4.w);
    }
    __syncthreads();

    const int wave  = t >> 6;
    const int lane  = t & 63;
    const int row16 = lane & 15;      // A row within tile / D col low bits
    const int kblk  = lane >> 4;      // 0..3: k-subblock / D row group
    const int rbase = blockIdx.x * 64 + wave * 16;

    int rowA = rbase + row16; if (rowA >= NN) rowA = NN - 1;   // clamped load
    const float* xrow = x + (size_t)rowA * FIN;

    f32x4 acc0 = {0,0,0,0}, acc1 = {0,0,0,0}, acc2 = {0,0,0,0}, acc3 = {0,0,0,0};

    #pragma unroll
    for (int ks = 0; ks < 4; ++ks) {
        const int k0 = ks * 32 + kblk * 8;           // this lane's 8 k's
        const float4 xa = *(const float4*)(xrow + k0);
        const float4 xb = *(const float4*)(xrow + k0 + 4);
        bf16x8 af;
        af[0] = (short)f2bf(xa.x); af[1] = (short)f2bf(xa.y);
        af[2] = (short)f2bf(xa.z); af[3] = (short)f2bf(xa.w);
        af[4] = (short)f2bf(xb.x); af[5] = (short)f2bf(xb.y);
        af[6] = (short)f2bf(xb.z); af[7] = (short)f2bf(xb.w);

        const bf16x8 b0 = *(const bf16x8*)(&SML[(0*16 + row16) * WT_LD + k0]);
        const bf16x8 b1 = *(const bf16x8*)(&SML[(1*16 + row16) * WT_LD + k0]);
        const bf16x8 b2 = *(const bf16x8*)(&SML[(2*16 + row16) * WT_LD + k0]);
        const bf16x8 b3 = *(const bf16x8*)(&SML[(3*16 + row16) * WT_LD + k0]);
        acc0 = __builtin_amdgcn_mfma_f32_16x16x32_bf16(af, b0, acc0, 0, 0, 0);
        acc1 = __builtin_amdgcn_mfma_f32_16x16x32_bf16(af, b1, acc1, 0, 0, 0);
        acc2 = __builtin_amdgcn_mfma_f32_16x16x32_bf16(af, b2, acc2, 0, 0, 0);
        acc3 = __builtin_amdgcn_mfma_f32_16x16x32_bf16(af, b3, acc3, 0, 0, 0);
    }

    // ---- att scalars from fp32 accums: ps/pd per D-row, reduce over cols -
    float as0 = att_src[ 0 + row16], as1 = att_src[16 + row16];
    float as2 = att_src[32 + row16], as3 = att_src[48 + row16];
    float ad0 = att_dst[ 0 + row16], ad1 = att_dst[16 + row16];
    float ad2 = att_dst[32 + row16], ad3 = att_dst[48 + row16];
    #pragma unroll
    for (int reg = 0; reg < 4; ++reg) {
        float p = acc0[reg]*as0 + acc1[reg]*as1 + acc2[reg]*as2 + acc3[reg]*as3;
        float q = acc0[reg]*ad0 + acc1[reg]*ad1 + acc2[reg]*ad2 + acc3[reg]*ad3;
        #pragma unroll
        for (int m = 1; m <= 8; m <<= 1) {           // reduce 16 col-lanes
            p += __shfl_xor(p, m, 64);
            q += __shfl_xor(q, m, 64);
        }
        if (row16 == 0) {
            const int r = rbase + kblk * 4 + reg;    // D row
            if (r < NN) { ssrc[r] = p; sdst[r] = q; }
        }
    }

    // ---- h write: transpose via LDS for coalesced 32B global stores ------
    unsigned short* hT = SML + 64 * WT_LD + wave * 1024;   // 16x64 ushorts
    #pragma unroll
    for (int reg = 0; reg < 4; ++reg) {
        const int rr = (kblk * 4 + reg) * 64;
        hT[rr +  0 + row16] = f2bf(acc0[reg]);
        hT[rr + 16 + row16] = f2bf(acc1[reg]);
        hT[rr + 32 + row16] = f2bf(acc2[reg]);
        hT[rr + 48 + row16] = f2bf(acc3[reg]);
    }
    __syncthreads();
    {
        const int rr = lane >> 2;                    // 0..15 tile row
        const int cc = (lane & 3) << 4;              // ushort col base
        const int grow = rbase + rr;
        if (grow < NN) {
            const uint4 v0 = *(const uint4*)(hT + rr * 64 + cc);
            const uint4 v1 = *(const uint4*)(hT + rr * 64 + cc + 8);
            *(uint4*)(hb + (size_t)grow * FOUT + cc)     = v0;
            *(uint4*)(hb + (size_t)grow * FOUT + cc + 8) = v1;
        }
    }
}

// ---------------- Kernel 3: per-dst aggregation (round-12 form) -----------
__global__ __launch_bounds__(256) void k_agg(
    const unsigned short* __restrict__ hb, const unsigned short* __restrict__ bkt,
    const int* __restrict__ counts, const float* __restrict__ ssrc,
    const float* __restrict__ sdst, const float* __restrict__ bias,
    float* __restrict__ out)
{
    const int r    = blockIdx.x & 7;          // dst range (XCD heuristic)
    const int wave = threadIdx.x >> 6;
    const int lane = threadIdx.x & 63;
    const int eq   = lane >> 3;               // slot-pair group 0..7
    const int c8   = lane & 7;                // col group (8 cols)
    const int c16  = c8 << 3;                 // col base
    const int wstride = (AGG_NBLK >> 3) * 4;  // 1024 wave-slots per range
    const float4 bLo = *(const float4*)(bias + c16);
    const float4 bHi = *(const float4*)(bias + c16 + 4);

    for (int local = (blockIdx.x >> 3) * 4 + wave; local < RSZ;
         local += 2 * wstride) {
        const int localB = local + wstride;
        const bool hasB  = localB < RSZ;
        const int nA   = r * RSZ + local;
        const int nB   = hasB ? r * RSZ + localB : nA;
        const int offA = nA << 6;             // ushort units
        const int offB = nB << 6;
        int cntA = counts[nA]; if (cntA > CAP) cntA = CAP;
        int cntB = hasB ? counts[nB] : 0; if (cntB > CAP) cntB = CAP;
        const float zdA = sdst[nA];
        const float zdB = sdst[nB];

        float accA[8] = {0,0,0,0,0,0,0,0};
        float accB[8] = {0,0,0,0,0,0,0,0};
        float asumA = 0.f, asumB = 0.f;

        const int nchA = (cntA + 15) >> 4;    // 16 slots per chunk
        const int nchB = (cntB + 15) >> 4;
        const int nch  = nchA > nchB ? nchA : nchB;   // <= 4

        for (int c = 0; c < nch; ++c) {
            const int s0 = (c << 4) + (eq << 1);   // this lane's 2 slots
            const unsigned wA = *(const unsigned*)(bkt + offA + s0);
            const unsigned wB = *(const unsigned*)(bkt + offB + s0);
            unsigned a0 = wA & 0xFFFFu, a1 = wA >> 16;
            unsigned b0 = wB & 0xFFFFu, b1 = wB >> 16;
            if (s0     >= cntA) a0 = 0u;          // clamp -> broadcast line
            if (s0 + 1 >= cntA) a1 = 0u;
            if (s0     >= cntB) b0 = 0u;
            if (s0 + 1 >= cntB) b1 = 0u;

            const float zA0 = ssrc[a0], zA1 = ssrc[a1];
            const float zB0 = ssrc[b0], zB1 = ssrc[b1];
            const uint4 hA0 = *(const uint4*)(hb + (size_t)a0 * FOUT + c16);
            const uint4 hA1 = *(const uint4*)(hb + (size_t)a1 * FOUT + c16);
            const uint4 hB0 = *(const uint4*)(hb + (size_t)b0 * FOUT + c16);
            const uint4 hB1 = *(const uint4*)(hb + (size_t)b1 * FOUT + c16);

            float sA0 = zA0 + zdA; sA0 = fmaxf(sA0, 0.2f * sA0);
            float sA1 = zA1 + zdA; sA1 = fmaxf(sA1, 0.2f * sA1);
            float sB0 = zB0 + zdB; sB0 = fmaxf(sB0, 0.2f * sB0);
            float sB1 = zB1 + zdB; sB1 = fmaxf(sB1, 0.2f * sB1);
            const float aA0 = (s0     < cntA) ? 1.f/(1.f+__expf(-sA0)) : 0.f;
            const float aA1 = (s0 + 1 < cntA) ? 1.f/(1.f+__expf(-sA1)) : 0.f;
            const float aB0 = (s0     < cntB) ? 1.f/(1.f+__expf(-sB0)) : 0.f;
            const float aB1 = (s0 + 1 < cntB) ? 1.f/(1.f+__expf(-sB1)) : 0.f;

            const unsigned uA0[4] = {hA0.x, hA0.y, hA0.z, hA0.w};
            const unsigned uA1[4] = {hA1.x, hA1.y, hA1.z, hA1.w};
            const unsigned uB0[4] = {hB0.x, hB0.y, hB0.z, hB0.w};
            const unsigned uB1[4] = {hB1.x, hB1.y, hB1.z, hB1.w};
            #pragma unroll
            for (int k = 0; k < 4; ++k) {
                accA[2*k]   += aA0 * bf2f((unsigned short)(uA0[k] & 0xFFFFu))
                             + aA1 * bf2f((unsigned short)(uA1[k] & 0xFFFFu));
                accA[2*k+1] += aA0 * bf2f((unsigned short)(uA0[k] >> 16))
                             + aA1 * bf2f((unsigned short)(uA1[k] >> 16));
                accB[2*k]   += aB0 * bf2f((unsigned short)(uB0[k] & 0xFFFFu))
                             + aB1 * bf2f((unsigned short)(uB1[k] & 0xFFFFu));
                accB[2*k+1] += aB0 * bf2f((unsigned short)(uB0[k] >> 16))
                             + aB1 * bf2f((unsigned short)(uB1[k] >> 16));
            }
            asumA += aA0 + aA1;
            asumB += aB0 + aB1;
        }

        #pragma unroll
        for (int m = 8; m <= 32; m <<= 1) {   // reduce across the 8 eq groups
            #pragma unroll
            for (int k = 0; k < 8; ++k) {
                accA[k] += __shfl_xor(accA[k], m, 64);
                accB[k] += __shfl_xor(accB[k], m, 64);
            }
            asumA += __shfl_xor(asumA, m, 64);
            asumB += __shfl_xor(asumB, m, 64);
        }

        if (eq == 0) {
            const float invA = 1.f / (asumA + 1e-8f);
            float4 lo, hi;
            lo.x = accA[0]*invA + bLo.x; lo.y = accA[1]*invA + bLo.y;
            lo.z = accA[2]*invA + bLo.z; lo.w = accA[3]*invA + bLo.w;
            hi.x = accA[4]*invA + bHi.x; hi.y = accA[5]*invA + bHi.y;
            hi.z = accA[6]*invA + bHi.z; hi.w = accA[7]*invA + bHi.w;
            *(float4*)(out + (size_t)nA * FOUT + c16)     = lo;
            *(float4*)(out + (size_t)nA * FOUT + c16 + 4) = hi;
            if (hasB) {
                const float invB = 1.f / (asumB + 1e-8f);
                lo.x = accB[0]*invB + bLo.x; lo.y = accB[1]*invB + bLo.y;
                lo.z = accB[2]*invB + bLo.z; lo.w = accB[3]*invB + bLo.w;
                hi.x = accB[4]*invB + bHi.x; hi.y = accB[5]*invB + bHi.y;
                hi.z = accB[6]*invB + bHi.z; hi.w = accB[7]*invB + bHi.w;
                *(float4*)(out + (size_t)nB * FOUT + c16)     = lo;
                *(float4*)(out + (size_t)nB * FOUT + c16 + 4) = hi;
            }
        }
    }
}

// ---------------- launch ---------------------------------------------------
extern "C" void kernel_launch(void* const* d_in, const int* in_sizes, int n_in,
                              void* d_out, int out_size, void* d_ws, size_t ws_size,
                              hipStream_t stream)
{
    const float* x       = (const float*)d_in[0];
    const int*   ei      = (const int*)  d_in[1];   // (2, NE) int32
    const float* W       = (const float*)d_in[2];
    const float* att_src = (const float*)d_in[3];
    const float* att_dst = (const float*)d_in[4];
    const float* bias    = (const float*)d_in[5];
    float* out = (float*)d_out;

    // workspace layout (~17.5 MB)
    unsigned short* hb  = (unsigned short*)d_ws;            // NN*FOUT bf16, 6.4MB
    float* ssrc         = (float*)(hb + (size_t)NN * FOUT);
    float* sdst         = ssrc + NN;
    int*   counts       = (int*)(sdst + NN);                // NN ints
    unsigned short* bkt = (unsigned short*)(counts + NN);   // NN*CAP ushort, 6.4MB
    unsigned int* epack = (unsigned int*)(bkt + (size_t)NN * CAP); // 4.0MB
    int* rangeCursor    = (int*)(epack + (size_t)NRG * CAPSEG);    // 196 ints

    const int* src = ei;
    const int* dst = ei + NE;

    // zero the per-range segment cursors (tiny)
    (void)hipMemsetAsync(rangeCursor, 0, NRG * sizeof(int), stream);

    k_binA<<<PA_NBLK, 1024, 0, stream>>>(src, dst, rangeCursor, epack);
    k_gemm_binB<<<FUSE_NBLK, 256, 0, stream>>>(x, W, att_src, att_dst,
                                               hb, ssrc, sdst,
                                               rangeCursor, epack,
                                               counts, bkt);
    k_agg<<<AGG_NBLK, 256, 0, stream>>>(hb, bkt, counts, ssrc, sdst,
                                        bias, out);
}